// Round 1
// baseline (83.130 us; speedup 1.0000x reference)
//
#include <hip/hip_runtime.h>
#include <math.h>

#define NJ 7
#define DTF 0.01f
#define GRAVF 9.81f
#define MIX(i,j) ((i)*((i)+1)/2 + (j))
#define SNC  15   // sn/cs stride (gcd(15,32)=1)
#define QST  9    // q/qd/rhs stride (gcd(9,32)=1)

__device__ __forceinline__ void cross3(const float* a, const float* b, float* o){
    o[0] = a[1]*b[2] - a[2]*b[1];
    o[1] = a[2]*b[0] - a[0]*b[2];
    o[2] = a[0]*b[1] - a[1]*b[0];
}
__device__ __forceinline__ void mv3(const float* E, const float* x, float* y){
    y[0] = E[0]*x[0] + E[1]*x[1] + E[2]*x[2];
    y[1] = E[3]*x[0] + E[4]*x[1] + E[5]*x[2];
    y[2] = E[6]*x[0] + E[7]*x[1] + E[8]*x[2];
}
__device__ __forceinline__ void mtv3(const float* E, const float* x, float* y){
    y[0] = E[0]*x[0] + E[3]*x[1] + E[6]*x[2];
    y[1] = E[1]*x[0] + E[4]*x[1] + E[7]*x[2];
    y[2] = E[2]*x[0] + E[5]*x[1] + E[8]*x[2];
}
__device__ __forceinline__ void symv(const float* S, const float* x, float* y){
    y[0] = S[0]*x[0] + S[1]*x[1] + S[2]*x[2];
    y[1] = S[1]*x[0] + S[3]*x[1] + S[4]*x[2];
    y[2] = S[2]*x[0] + S[4]*x[1] + S[5]*x[2];
}
__device__ __forceinline__ void mm3(const float* A, const float* B, float* o){
#pragma unroll
    for (int r = 0; r < 3; r++)
#pragma unroll
        for (int c = 0; c < 3; c++)
            o[r*3+c] = A[r*3]*B[c] + A[r*3+1]*B[3+c] + A[r*3+2]*B[6+c];
}
// o = E^T X E
__device__ __forceinline__ void congr(const float* E, const float* X, float* o){
    float t[9];
#pragma unroll
    for (int r = 0; r < 3; r++)
#pragma unroll
        for (int c = 0; c < 3; c++)
            t[r*3+c] = E[r]*X[c] + E[3+r]*X[3+c] + E[6+r]*X[6+c];
    mm3(t, E, o);
}
// E_i = R(q_i)^T @ R_tree[i]
__device__ __forceinline__ void makeE(const float* a, const float* __restrict__ Rt,
                                      float s, float c, float* E){
    float omc = 1.0f - c;
    float RT[9];
    RT[0] = c + omc*a[0]*a[0];       RT[1] =  s*a[2] + omc*a[0]*a[1]; RT[2] = -s*a[1] + omc*a[0]*a[2];
    RT[3] = -s*a[2] + omc*a[1]*a[0]; RT[4] = c + omc*a[1]*a[1];       RT[5] =  s*a[0] + omc*a[1]*a[2];
    RT[6] =  s*a[1] + omc*a[2]*a[0]; RT[7] = -s*a[0] + omc*a[2]*a[1]; RT[8] = c + omc*a[2]*a[2];
    float Rl[9];
#pragma unroll
    for (int k = 0; k < 9; k++) Rl[k] = Rt[k];
    mm3(RT, Rl, E);
}
// body spatial-inertia params (wave-uniform scalar loads)
__device__ __forceinline__ void bodyI(const float* __restrict__ g_I, int i,
                                      float* SA, float* h, float& m){
    const float* I6 = g_I + i*36;
    SA[0]=I6[0]; SA[1]=I6[1]; SA[2]=I6[2];
    SA[3]=I6[7]; SA[4]=I6[8]; SA[5]=I6[14];
    h[0]=I6[16]; h[1]=I6[5]; h[2]=I6[9];
    m = I6[21];
}

__constant__ float QL_c[NJ] = {-2.9671f,-1.8326f,-2.9671f,-3.1416f,-2.9671f,-0.0873f,-2.9671f};
__constant__ float QU_c[NJ] = { 2.9671f, 1.8326f, 2.9671f, 0.0f,    2.9671f, 3.8223f, 2.9671f};

// Block = 128 = 2 waves on the SAME 64 elements. Grid gives only 2 waves/SIMD,
// so everything hinges on the per-wave serial chain: ALL per-joint loops are
// fully unrolled so F / M live in REGISTERS (no s_F / s_M LDS round-trips on
// the dependency chain), and all model-constant loads become hoistable
// straight-line scalar loads.
// Wave 0: RNEA -> rhs (LDS); publishes q/qd/sincos; then retires.
// Wave 1: CRBA -> M -> Cholesky (regs) -> [barrier] -> solves + integrate + store.
__global__ __launch_bounds__(128, 2)
void panda_step(const float* __restrict__ x, const float* __restrict__ u,
                const float* __restrict__ g_ax, const float* __restrict__ g_Rt,
                const float* __restrict__ g_pt, const float* __restrict__ g_I,
                float* __restrict__ out, int B)
{
    __shared__ float s_snc[64*SNC];   // 3840 B (sn[0:7), cs[7:14))
    __shared__ float s_q  [64*QST];   // 2304 B
    __shared__ float s_qd [64*QST];   // 2304 B
    __shared__ float s_rhs[64*QST];   // 2304 B

    const int role = threadIdx.x >> 6;      // wave-uniform
    const int lane = threadIdx.x & 63;
    const int e    = blockIdx.x*64 + lane;
    const bool act = (e < B);

    // wave-uniform model constants, shared by both roles; issued before the
    // barrier so SMEM latency hides under phase 0.
    float a_all[3*NJ], p_all[3*NJ];
#pragma unroll
    for (int j = 0; j < 3*NJ; j++){ a_all[j] = g_ax[j]; p_all[j] = g_pt[j]; }
    // role-1 leaf-body inertia prefetch (uniform scalar loads; dead on role 0)
    float SA[6], hc[3], mc;
    bodyI(g_I, 6, SA, hc, mc);

    float q[NJ], qd[NJ], sn[NJ], cs[NJ], uu[NJ];
    if (act && role == 0){
        const float2* x2 = (const float2*)(x + e*14);
        float xl[14];
#pragma unroll
        for (int i = 0; i < 7; i++){ float2 v = x2[i]; xl[2*i] = v.x; xl[2*i+1] = v.y; }
#pragma unroll
        for (int i = 0; i < NJ; i++){
            q[i]  = fminf(fmaxf(xl[i], QL_c[i]), QU_c[i]);
            qd[i] = xl[NJ + i];
            uu[i] = u[e*NJ + i];
            __sincosf(q[i], &sn[i], &cs[i]);
            s_snc[lane*SNC + i]     = sn[i];
            s_snc[lane*SNC + 7 + i] = cs[i];
            s_q [lane*QST + i]      = q[i];
            s_qd[lane*QST + i]      = qd[i];
        }
    }
    __syncthreads();   // publish sn/cs/q/qd

    float Mx[28];      // role-1 Cholesky factor; must survive the 2nd barrier
    if (act){
      if (role == 1){
        // =================== CRBA (registers) + Cholesky ===================
        float sn1[NJ], cs1[NJ];
#pragma unroll
        for (int i = 0; i < NJ; i++){
            sn1[i] = s_snc[lane*SNC + i];
            cs1[i] = s_snc[lane*SNC + 7 + i];
        }
        float Fb[6*NJ];
#pragma unroll
        for (int i = NJ-1; i >= 0; --i){
            float a[3] = { a_all[3*i], a_all[3*i+1], a_all[3*i+2] };
            // F_i = [SA a ; a x hc]
            float Ft[3]; symv(SA, a, Ft);
            Fb[i*6+0]=Ft[0]; Fb[i*6+1]=Ft[1]; Fb[i*6+2]=Ft[2];
            Fb[i*6+3] = a[1]*hc[2] - a[2]*hc[1];
            Fb[i*6+4] = a[2]*hc[0] - a[0]*hc[2];
            Fb[i*6+5] = a[0]*hc[1] - a[1]*hc[0];
            // M column i (register accumulation, static indices)
#pragma unroll
            for (int k = i; k < NJ; ++k)
                Mx[MIX(k,i)] = a[0]*Fb[k*6] + a[1]*Fb[k*6+1] + a[2]*Fb[k*6+2];
            if (i > 0){
                float p[3] = { p_all[3*i], p_all[3*i+1], p_all[3*i+2] };
                float E[9]; makeE(a, g_Rt + 9*i, sn1[i], cs1[i], E);
                float SAm[6], hm[3], mm_;
                bodyI(g_I, i-1, SAm, hm, mm_);
                float Af[9] = {SA[0],SA[1],SA[2], SA[1],SA[3],SA[4], SA[2],SA[4],SA[5]};
                float Ap[9]; congr(E, Af, Ap);
                float hr[3]; mtv3(E, hc, hr);
                float hpd = hr[0]*p[0]+hr[1]*p[1]+hr[2]*p[2];
                float ppd = p[0]*p[0]+p[1]*p[1]+p[2]*p[2];
                float dga = 2.0f*hpd + mc*ppd;
                SA[0] = Ap[0] - 2.0f*p[0]*hr[0] - mc*p[0]*p[0] + dga + SAm[0];
                SA[1] = Ap[1] - p[0]*hr[1] - hr[0]*p[1] - mc*p[0]*p[1] + SAm[1];
                SA[2] = Ap[2] - p[0]*hr[2] - hr[0]*p[2] - mc*p[0]*p[2] + SAm[2];
                SA[3] = Ap[4] - 2.0f*p[1]*hr[1] - mc*p[1]*p[1] + dga + SAm[3];
                SA[4] = Ap[5] - p[1]*hr[2] - hr[1]*p[2] - mc*p[1]*p[2] + SAm[4];
                SA[5] = Ap[8] - 2.0f*p[2]*hr[2] - mc*p[2]*p[2] + dga + SAm[5];
                hc[0] = hr[0] + mc*p[0] + hm[0];
                hc[1] = hr[1] + mc*p[1] + hm[1];
                hc[2] = hr[2] + mc*p[2] + hm[2];
                mc += mm_;
                // transform active F_k into frame i-1 (registers)
#pragma unroll
                for (int k = i; k < NJ; ++k){
                    float ft[3] = {Fb[k*6+0], Fb[k*6+1], Fb[k*6+2]};
                    float fb2[3] = {Fb[k*6+3], Fb[k*6+4], Fb[k*6+5]};
                    float tm[3], tf[3], cp[3];
                    mtv3(E, ft, tm); mtv3(E, fb2, tf);
                    cross3(p, tf, cp);
                    Fb[k*6+0]=tm[0]+cp[0]; Fb[k*6+1]=tm[1]+cp[1]; Fb[k*6+2]=tm[2]+cp[2];
                    Fb[k*6+3]=tf[0];       Fb[k*6+4]=tf[1];       Fb[k*6+5]=tf[2];
                }
            }
        }
        // ridge + Cholesky factor in registers
#pragma unroll
        for (int i = 0; i < NJ; i++) Mx[MIX(i,i)] += 1e-8f;
#pragma unroll
        for (int k = 0; k < NJ; k++){
            float d = Mx[MIX(k,k)];
#pragma unroll
            for (int j = 0; j < NJ; j++) if (j < k) d -= Mx[MIX(k,j)]*Mx[MIX(k,j)];
            float linv = __builtin_amdgcn_rsqf(d);
            Mx[MIX(k,k)] = linv;
#pragma unroll
            for (int i2 = k+1; i2 < NJ; i2++){
                float s2 = Mx[MIX(i2,k)];
#pragma unroll
                for (int j = 0; j < NJ; j++) if (j < k) s2 -= Mx[MIX(i2,j)]*Mx[MIX(k,j)];
                Mx[MIX(i2,k)] = s2 * linv;
            }
        }
      } else {
        // =================== RNEA (registers) ===================
        float Fb[6*NJ];
        float w[3]  = {0.f,0.f,0.f}, vl[3] = {0.f,0.f,0.f};
        float aw[3] = {0.f,0.f,0.f}, avv[3] = {0.f,0.f,GRAVF};
#pragma unroll
        for (int i = 0; i < NJ; ++i){
            float a[3] = { a_all[3*i], a_all[3*i+1], a_all[3*i+2] };
            float p[3] = { p_all[3*i], p_all[3*i+1], p_all[3*i+2] };
            float qdi = qd[i];
            float E[9]; makeE(a, g_Rt + 9*i, sn[i], cs[i], E);
            float tw[3]; mv3(E, w, tw);
            float nw[3] = { tw[0]+a[0]*qdi, tw[1]+a[1]*qdi, tw[2]+a[2]*qdi };
            float cwp[3]; cross3(w, p, cwp);
            float t1[3] = { vl[0]+cwp[0], vl[1]+cwp[1], vl[2]+cwp[2] };
            float nvl[3]; mv3(E, t1, nvl);
            float taw[3]; mv3(E, aw, taw);
            float cna[3]; cross3(nw, a, cna);
            float naw[3] = { taw[0]+qdi*cna[0], taw[1]+qdi*cna[1], taw[2]+qdi*cna[2] };
            float cap[3]; cross3(aw, p, cap);
            float t2[3] = { avv[0]+cap[0], avv[1]+cap[1], avv[2]+cap[2] };
            float tav[3]; mv3(E, t2, tav);
            float cva[3]; cross3(nvl, a, cva);
            float nav[3] = { tav[0]+qdi*cva[0], tav[1]+qdi*cva[1], tav[2]+qdi*cva[2] };
            float SAi[6], hi[3], mi; bodyI(g_I, i, SAi, hi, mi);
            float Ivt[3], Iat[3], hxv[3], hxa[3];
            symv(SAi, nw, Ivt);  cross3(hi, nvl, hxv);
            symv(SAi, naw, Iat); cross3(hi, nav, hxa);
#pragma unroll
            for (int k = 0; k < 3; k++){ Ivt[k] += hxv[k]; Iat[k] += hxa[k]; }
            float hxw[3], hxaw[3];
            cross3(hi, nw, hxw); cross3(hi, naw, hxaw);
            float Ivb[3] = { mi*nvl[0]-hxw[0], mi*nvl[1]-hxw[1], mi*nvl[2]-hxw[2] };
            float Iab[3] = { mi*nav[0]-hxaw[0], mi*nav[1]-hxaw[1], mi*nav[2]-hxaw[2] };
            float c1[3], c2[3], c3[3];
            cross3(nw, Ivt, c1); cross3(nvl, Ivb, c2); cross3(nw, Ivb, c3);
            Fb[i*6+0] = Iat[0]+c1[0]+c2[0];
            Fb[i*6+1] = Iat[1]+c1[1]+c2[1];
            Fb[i*6+2] = Iat[2]+c1[2]+c2[2];
            Fb[i*6+3] = Iab[0]+c3[0];
            Fb[i*6+4] = Iab[1]+c3[1];
            Fb[i*6+5] = Iab[2]+c3[2];
#pragma unroll
            for (int k = 0; k < 3; k++){ w[k]=nw[k]; vl[k]=nvl[k]; aw[k]=naw[k]; avv[k]=nav[k]; }
        }
        // backward fold (registers; E recomputed — keeps role-0 VGPR low)
#pragma unroll
        for (int i = NJ-1; i >= 0; --i){
            float a[3] = { a_all[3*i], a_all[3*i+1], a_all[3*i+2] };
            float f0=Fb[i*6+0], f1=Fb[i*6+1], f2=Fb[i*6+2];
            s_rhs[lane*QST + i] = uu[i] - (a[0]*f0 + a[1]*f1 + a[2]*f2);
            if (i > 0){
                float p[3] = { p_all[3*i], p_all[3*i+1], p_all[3*i+2] };
                float E[9]; makeE(a, g_Rt + 9*i, sn[i], cs[i], E);
                float ftop[3] = {f0, f1, f2};
                float fbot[3] = {Fb[i*6+3], Fb[i*6+4], Fb[i*6+5]};
                float tm[3], tf[3], cp[3];
                mtv3(E, ftop, tm); mtv3(E, fbot, tf);
                cross3(p, tf, cp);
                Fb[(i-1)*6+0] += tm[0]+cp[0];
                Fb[(i-1)*6+1] += tm[1]+cp[1];
                Fb[(i-1)*6+2] += tm[2]+cp[2];
                Fb[(i-1)*6+3] += tf[0];
                Fb[(i-1)*6+4] += tf[1];
                Fb[(i-1)*6+5] += tf[2];
            }
        }
      }
    }

    __syncthreads();   // publish rhs

    if (act && role == 1){
        // ======== triangular solves + integrate + store (Mx still in regs) ========
        float rhs[NJ];
#pragma unroll
        for (int i = 0; i < NJ; i++) rhs[i] = s_rhs[lane*QST + i];
        float y[NJ];
#pragma unroll
        for (int i = 0; i < NJ; i++){
            float s2 = rhs[i];
#pragma unroll
            for (int j = 0; j < NJ; j++) if (j < i) s2 -= Mx[MIX(i,j)]*y[j];
            y[i] = s2 * Mx[MIX(i,i)];
        }
        float z[NJ];
#pragma unroll
        for (int i = NJ-1; i >= 0; i--){
            float s2 = y[i];
#pragma unroll
            for (int j = NJ-1; j >= 0; j--) if (j > i) s2 -= Mx[MIX(j,i)]*z[j];
            z[i] = s2 * Mx[MIX(i,i)];
        }
        float o14[14];
#pragma unroll
        for (int i = 0; i < NJ; i++){
            float qv  = s_q [lane*QST + i];
            float qdv = s_qd[lane*QST + i];
            float qdn = qdv + DTF*z[i];
            o14[i]      = qv + DTF*qdn;
            o14[NJ + i] = qdn;
        }
        float2* o2 = (float2*)(out + e*14);
#pragma unroll
        for (int i = 0; i < 7; i++){ float2 v; v.x = o14[2*i]; v.y = o14[2*i+1]; o2[i] = v; }
    }
}

extern "C" void kernel_launch(void* const* d_in, const int* in_sizes, int n_in,
                              void* d_out, int out_size, void* d_ws, size_t ws_size,
                              hipStream_t stream) {
    const float* x   = (const float*)d_in[0];
    const float* u   = (const float*)d_in[1];
    const float* ax  = (const float*)d_in[2];
    const float* Rt  = (const float*)d_in[3];
    const float* pt  = (const float*)d_in[4];
    const float* Isp = (const float*)d_in[5];
    float* out = (float*)d_out;
    int B = in_sizes[0] / 14;
    int grid = (B + 63) / 64;
    hipLaunchKernelGGL(panda_step, dim3(grid), dim3(128), 0, stream,
                       x, u, ax, Rt, pt, Isp, out, B);
}

// Round 2
// 79.698 us; speedup vs baseline: 1.0431x; 1.0431x over previous
//
#include <hip/hip_runtime.h>
#include <math.h>

#define NJ 7
#define DTF 0.01f
#define GRAVF 9.81f
#define MIX(i,j) ((i)*((i)+1)/2 + (j))
#define MPAD 29   // s_M stride (gcd(29,32)=1)
#define FSTR 43   // per-lane F stride (gcd(43,32)=1)
#define SNC  15   // sn/cs stride (gcd(15,32)=1)
#define MST  23   // q[0:7) qd[7:14) rhs[14:21), stride 23 (gcd(23,32)=1)

__device__ __forceinline__ void cross3(const float* a, const float* b, float* o){
    o[0] = a[1]*b[2] - a[2]*b[1];
    o[1] = a[2]*b[0] - a[0]*b[2];
    o[2] = a[0]*b[1] - a[1]*b[0];
}
__device__ __forceinline__ void mv3(const float* E, const float* x, float* y){
    y[0] = E[0]*x[0] + E[1]*x[1] + E[2]*x[2];
    y[1] = E[3]*x[0] + E[4]*x[1] + E[5]*x[2];
    y[2] = E[6]*x[0] + E[7]*x[1] + E[8]*x[2];
}
__device__ __forceinline__ void mtv3(const float* E, const float* x, float* y){
    y[0] = E[0]*x[0] + E[3]*x[1] + E[6]*x[2];
    y[1] = E[1]*x[0] + E[4]*x[1] + E[7]*x[2];
    y[2] = E[2]*x[0] + E[5]*x[1] + E[8]*x[2];
}
__device__ __forceinline__ void symv(const float* S, const float* x, float* y){
    y[0] = S[0]*x[0] + S[1]*x[1] + S[2]*x[2];
    y[1] = S[1]*x[0] + S[3]*x[1] + S[4]*x[2];
    y[2] = S[2]*x[0] + S[4]*x[1] + S[5]*x[2];
}
__device__ __forceinline__ void mm3(const float* A, const float* B, float* o){
#pragma unroll
    for (int r = 0; r < 3; r++)
#pragma unroll
        for (int c = 0; c < 3; c++)
            o[r*3+c] = A[r*3]*B[c] + A[r*3+1]*B[3+c] + A[r*3+2]*B[6+c];
}
// o = E^T X E
__device__ __forceinline__ void congr(const float* E, const float* X, float* o){
    float t[9];
#pragma unroll
    for (int r = 0; r < 3; r++)
#pragma unroll
        for (int c = 0; c < 3; c++)
            t[r*3+c] = E[r]*X[c] + E[3+r]*X[3+c] + E[6+r]*X[6+c];
    mm3(t, E, o);
}
// E = R(q)^T @ R_tree, with R_tree already in registers
__device__ __forceinline__ void makeE_reg(const float* a, const float* Rl,
                                          float s, float c, float* E){
    float omc = 1.0f - c;
    float RT[9];
    RT[0] = c + omc*a[0]*a[0];       RT[1] =  s*a[2] + omc*a[0]*a[1]; RT[2] = -s*a[1] + omc*a[0]*a[2];
    RT[3] = -s*a[2] + omc*a[1]*a[0]; RT[4] = c + omc*a[1]*a[1];       RT[5] =  s*a[0] + omc*a[1]*a[2];
    RT[6] =  s*a[1] + omc*a[2]*a[0]; RT[7] = -s*a[0] + omc*a[2]*a[1]; RT[8] = c + omc*a[2]*a[2];
    mm3(RT, Rl, E);
}
// body spatial-inertia params (wave-uniform scalar loads)
__device__ __forceinline__ void bodyI(const float* __restrict__ g_I, int i,
                                      float* SA, float* h, float& m){
    const float* I6 = g_I + i*36;
    SA[0]=I6[0]; SA[1]=I6[1]; SA[2]=I6[2];
    SA[3]=I6[7]; SA[4]=I6[8]; SA[5]=I6[14];
    h[0]=I6[16]; h[1]=I6[5]; h[2]=I6[9];
    m = I6[21];
}

__constant__ float QL_c[NJ] = {-2.9671f,-1.8326f,-2.9671f,-3.1416f,-2.9671f,-0.0873f,-2.9671f};
__constant__ float QU_c[NJ] = { 2.9671f, 1.8326f, 2.9671f, 0.0f,    2.9671f, 3.8223f, 2.9671f};

// Round-0 structure (rolled loops, ~10 KB I$-resident) with two targeted fixes:
//  (1) software-pipelined rotation prefetch of per-joint constants in all three
//      rolled loops — joint i+/-1's a/p/R/sincos/bodyI are issued at the top of
//      iteration i, hiding the ~200cy scalar-load latency under compute;
//  (2) the Cholesky factor stays in role-1 registers across the final barrier
//      and role 1 does solve+integrate+store itself (removes the s_M
//      write->barrier->read round trip; q/qd cross via LDS instead).
__global__ __launch_bounds__(128, 2)
void panda_step(const float* __restrict__ x, const float* __restrict__ u,
                const float* __restrict__ g_ax, const float* __restrict__ g_Rt,
                const float* __restrict__ g_pt, const float* __restrict__ g_I,
                float* __restrict__ out, int B)
{
    __shared__ float s_M   [64*MPAD];  // 7424 B  (CRBA M scratch)
    __shared__ float s_F   [2*64*FSTR];// 22016 B (role0: RNEA F, role1: CRBA F)
    __shared__ float s_snc [64*SNC];   // 3840 B  (sn[0:7) cs[7:14))
    __shared__ float s_misc[64*MST];   // 5888 B  (q, qd, rhs)
    // total 39168 B -> 4 blocks/CU (grid = 4 blocks/CU exactly)

    const int role = threadIdx.x >> 6;      // wave-uniform
    const int lane = threadIdx.x & 63;
    const int e    = blockIdx.x*64 + lane;
    const bool act = (e < B);

    // --- cross-barrier prefetch registers (role-dependent meaning) ---
    // role1: aC/pC/RC = joint 6, SAx/hx/mx = bodyI(5), SA/hc/mc = bodyI(6)
    // role0: aC/pC/RC = joint 0, SAx/hx/mx = bodyI(0)
    float aC[3], pC[3], RC[9];
    float SAx[6], hx[3], mx;
    float SA[6], hc[3], mc;
    float snC = 0.f, csC = 0.f, qdC = 0.f;

    if (role == 1){
        bodyI(g_I, 6, SA, hc, mc);
        bodyI(g_I, 5, SAx, hx, mx);
        aC[0]=g_ax[18]; aC[1]=g_ax[19]; aC[2]=g_ax[20];
        pC[0]=g_pt[18]; pC[1]=g_pt[19]; pC[2]=g_pt[20];
#pragma unroll
        for (int k = 0; k < 9; k++) RC[k] = g_Rt[54+k];
    } else {
        bodyI(g_I, 0, SAx, hx, mx);
        aC[0]=g_ax[0]; aC[1]=g_ax[1]; aC[2]=g_ax[2];
        pC[0]=g_pt[0]; pC[1]=g_pt[1]; pC[2]=g_pt[2];
#pragma unroll
        for (int k = 0; k < 9; k++) RC[k] = g_Rt[k];
        if (act){
            const float2* x2 = (const float2*)(x + e*14);
            float xl[14];
#pragma unroll
            for (int i = 0; i < 7; i++){ float2 v = x2[i]; xl[2*i] = v.x; xl[2*i+1] = v.y; }
#pragma unroll
            for (int i = 0; i < NJ; i++){
                float qi  = fminf(fmaxf(xl[i], QL_c[i]), QU_c[i]);
                float qdi = xl[NJ + i];
                float s, c; __sincosf(qi, &s, &c);
                s_snc [lane*SNC + i]      = s;
                s_snc [lane*SNC + 7 + i]  = c;
                s_misc[lane*MST + i]      = qi;
                s_misc[lane*MST + 7 + i]  = qdi;
                s_misc[lane*MST + 14 + i] = u[e*NJ + i];
                if (i == 0){ snC = s; csC = c; qdC = qdi; }   // static peel
            }
        }
    }
    __syncthreads();   // publish sn/cs/q/qd/rhs(=u)

    float Mx[28];      // role-1 Cholesky factor; survives 2nd barrier in regs
    if (act){
      if (role == 1){
        // =================== CRBA (rolled, prefetch-pipelined) ===================
        float* Fb = &s_F[64*FSTR + lane*FSTR];
        snC = s_snc[lane*SNC + 6];
        csC = s_snc[lane*SNC + 13];
#pragma unroll 1
        for (int i = NJ-1; i >= 0; --i){
            // prefetch joint i-1's constants (consumed next iteration)
            float aN[3], pN[3], RN[9], snN, csN, SAxN[6], hxN[3], mxN;
            if (i > 0){
                const int b3 = 3*(i-1), b9 = 9*(i-1);
                aN[0]=g_ax[b3]; aN[1]=g_ax[b3+1]; aN[2]=g_ax[b3+2];
                pN[0]=g_pt[b3]; pN[1]=g_pt[b3+1]; pN[2]=g_pt[b3+2];
#pragma unroll
                for (int k = 0; k < 9; k++) RN[k] = g_Rt[b9+k];
                snN = s_snc[lane*SNC + (i-1)];
                csN = s_snc[lane*SNC + 6 + i];
                bodyI(g_I, (i >= 2) ? (i-2) : 0, SAxN, hxN, mxN);
            }
            // F_i = [SA a ; a x hc]
            float Ft[3]; symv(SA, aC, Ft);
            Fb[i*6+0]=Ft[0]; Fb[i*6+1]=Ft[1]; Fb[i*6+2]=Ft[2];
            Fb[i*6+3] = aC[1]*hc[2] - aC[2]*hc[1];
            Fb[i*6+4] = aC[2]*hc[0] - aC[0]*hc[2];
            Fb[i*6+5] = aC[0]*hc[1] - aC[1]*hc[0];
            // M column i
#pragma unroll 1
            for (int k = i; k < NJ; ++k){
                float f0=Fb[k*6], f1=Fb[k*6+1], f2=Fb[k*6+2];
                s_M[lane*MPAD + k*(k+1)/2 + i] = aC[0]*f0 + aC[1]*f1 + aC[2]*f2;
            }
            if (i > 0){
                float E[9]; makeE_reg(aC, RC, snC, csC, E);
                float Af[9] = {SA[0],SA[1],SA[2], SA[1],SA[3],SA[4], SA[2],SA[4],SA[5]};
                float Ap[9]; congr(E, Af, Ap);
                float hr[3]; mtv3(E, hc, hr);
                float hpd = hr[0]*pC[0]+hr[1]*pC[1]+hr[2]*pC[2];
                float ppd = pC[0]*pC[0]+pC[1]*pC[1]+pC[2]*pC[2];
                float dga = 2.0f*hpd + mc*ppd;
                SA[0] = Ap[0] - 2.0f*pC[0]*hr[0] - mc*pC[0]*pC[0] + dga + SAx[0];
                SA[1] = Ap[1] - pC[0]*hr[1] - hr[0]*pC[1] - mc*pC[0]*pC[1] + SAx[1];
                SA[2] = Ap[2] - pC[0]*hr[2] - hr[0]*pC[2] - mc*pC[0]*pC[2] + SAx[2];
                SA[3] = Ap[4] - 2.0f*pC[1]*hr[1] - mc*pC[1]*pC[1] + dga + SAx[3];
                SA[4] = Ap[5] - pC[1]*hr[2] - hr[1]*pC[2] - mc*pC[1]*pC[2] + SAx[4];
                SA[5] = Ap[8] - 2.0f*pC[2]*hr[2] - mc*pC[2]*pC[2] + dga + SAx[5];
                hc[0] = hr[0] + mc*pC[0] + hx[0];
                hc[1] = hr[1] + mc*pC[1] + hx[1];
                hc[2] = hr[2] + mc*pC[2] + hx[2];
                mc += mx;
                // transform active F_k into frame i-1
#pragma unroll 1
                for (int k = i; k < NJ; ++k){
                    float ft[3]  = {Fb[k*6+0], Fb[k*6+1], Fb[k*6+2]};
                    float fb2[3] = {Fb[k*6+3], Fb[k*6+4], Fb[k*6+5]};
                    float tm[3], tf[3], cp[3];
                    mtv3(E, ft, tm); mtv3(E, fb2, tf);
                    cross3(pC, tf, cp);
                    Fb[k*6+0]=tm[0]+cp[0]; Fb[k*6+1]=tm[1]+cp[1]; Fb[k*6+2]=tm[2]+cp[2];
                    Fb[k*6+3]=tf[0];       Fb[k*6+4]=tf[1];       Fb[k*6+5]=tf[2];
                }
                // rotate prefetched set into place
#pragma unroll
                for (int k = 0; k < 3; k++){ aC[k]=aN[k]; pC[k]=pN[k]; hx[k]=hxN[k]; }
#pragma unroll
                for (int k = 0; k < 9; k++) RC[k]=RN[k];
#pragma unroll
                for (int k = 0; k < 6; k++) SAx[k]=SAxN[k];
                snC=snN; csC=csN; mx=mxN;
            }
        }
        // ridge + Cholesky factor in registers (stays in regs through barrier)
#pragma unroll
        for (int j = 0; j < 28; j++) Mx[j] = s_M[lane*MPAD + j];
#pragma unroll
        for (int i = 0; i < NJ; i++) Mx[MIX(i,i)] += 1e-8f;
#pragma unroll
        for (int k = 0; k < NJ; k++){
            float d = Mx[MIX(k,k)];
#pragma unroll
            for (int j = 0; j < NJ; j++) if (j < k) d -= Mx[MIX(k,j)]*Mx[MIX(k,j)];
            float linv = __builtin_amdgcn_rsqf(d);
            Mx[MIX(k,k)] = linv;
#pragma unroll
            for (int i2 = k+1; i2 < NJ; i2++){
                float s2 = Mx[MIX(i2,k)];
#pragma unroll
                for (int j = 0; j < NJ; j++) if (j < k) s2 -= Mx[MIX(i2,j)]*Mx[MIX(k,j)];
                Mx[MIX(i2,k)] = s2 * linv;
            }
        }
      } else {
        // =================== RNEA forward (rolled, prefetch-pipelined) ===========
        float* Fb = &s_F[lane*FSTR];
        float w[3]  = {0.f,0.f,0.f}, vl[3] = {0.f,0.f,0.f};
        float aw[3] = {0.f,0.f,0.f}, avv[3] = {0.f,0.f,GRAVF};
#pragma unroll 1
        for (int i = 0; i < NJ; ++i){
            // prefetch joint i+1 (consumed next iteration)
            float aN[3], pN[3], RN[9], snN, csN, qdN, SAxN[6], hxN[3], mxN;
            if (i < NJ-1){
                const int b3 = 3*(i+1), b9 = 9*(i+1);
                aN[0]=g_ax[b3]; aN[1]=g_ax[b3+1]; aN[2]=g_ax[b3+2];
                pN[0]=g_pt[b3]; pN[1]=g_pt[b3+1]; pN[2]=g_pt[b3+2];
#pragma unroll
                for (int k = 0; k < 9; k++) RN[k] = g_Rt[b9+k];
                snN = s_snc [lane*SNC + i + 1];
                csN = s_snc [lane*SNC + 8 + i];
                qdN = s_misc[lane*MST + 8 + i];
                bodyI(g_I, i+1, SAxN, hxN, mxN);
            }
            float E[9]; makeE_reg(aC, RC, snC, csC, E);
            float tw[3]; mv3(E, w, tw);
            float nw[3] = { tw[0]+aC[0]*qdC, tw[1]+aC[1]*qdC, tw[2]+aC[2]*qdC };
            float cwp[3]; cross3(w, pC, cwp);
            float t1[3] = { vl[0]+cwp[0], vl[1]+cwp[1], vl[2]+cwp[2] };
            float nvl[3]; mv3(E, t1, nvl);
            float taw[3]; mv3(E, aw, taw);
            float cna[3]; cross3(nw, aC, cna);
            float naw[3] = { taw[0]+qdC*cna[0], taw[1]+qdC*cna[1], taw[2]+qdC*cna[2] };
            float cap[3]; cross3(aw, pC, cap);
            float t2[3] = { avv[0]+cap[0], avv[1]+cap[1], avv[2]+cap[2] };
            float tav[3]; mv3(E, t2, tav);
            float cva[3]; cross3(nvl, aC, cva);
            float nav[3] = { tav[0]+qdC*cva[0], tav[1]+qdC*cva[1], tav[2]+qdC*cva[2] };
            float Ivt[3], Iat[3], hxv[3], hxa[3];
            symv(SAx, nw,  Ivt); cross3(hx, nvl, hxv);
            symv(SAx, naw, Iat); cross3(hx, nav, hxa);
#pragma unroll
            for (int k = 0; k < 3; k++){ Ivt[k] += hxv[k]; Iat[k] += hxa[k]; }
            float hxw[3], hxaw[3];
            cross3(hx, nw, hxw); cross3(hx, naw, hxaw);
            float Ivb[3] = { mx*nvl[0]-hxw[0],  mx*nvl[1]-hxw[1],  mx*nvl[2]-hxw[2]  };
            float Iab[3] = { mx*nav[0]-hxaw[0], mx*nav[1]-hxaw[1], mx*nav[2]-hxaw[2] };
            float c1[3], c2[3], c3[3];
            cross3(nw, Ivt, c1); cross3(nvl, Ivb, c2); cross3(nw, Ivb, c3);
            Fb[i*6+0] = Iat[0]+c1[0]+c2[0];
            Fb[i*6+1] = Iat[1]+c1[1]+c2[1];
            Fb[i*6+2] = Iat[2]+c1[2]+c2[2];
            Fb[i*6+3] = Iab[0]+c3[0];
            Fb[i*6+4] = Iab[1]+c3[1];
            Fb[i*6+5] = Iab[2]+c3[2];
#pragma unroll
            for (int k = 0; k < 3; k++){ w[k]=nw[k]; vl[k]=nvl[k]; aw[k]=naw[k]; avv[k]=nav[k]; }
            if (i < NJ-1){
#pragma unroll
                for (int k = 0; k < 3; k++){ aC[k]=aN[k]; pC[k]=pN[k]; hx[k]=hxN[k]; }
#pragma unroll
                for (int k = 0; k < 9; k++) RC[k]=RN[k];
#pragma unroll
                for (int k = 0; k < 6; k++) SAx[k]=SAxN[k];
                snC=snN; csC=csN; qdC=qdN; mx=mxN;
            }
        }
        // ============ RNEA backward (C regs still hold joint 6) ============
#pragma unroll 1
        for (int i = NJ-1; i >= 0; --i){
            float aN[3], pN[3], RN[9], snN, csN;
            if (i > 0){
                const int b3 = 3*(i-1), b9 = 9*(i-1);
                aN[0]=g_ax[b3]; aN[1]=g_ax[b3+1]; aN[2]=g_ax[b3+2];
                pN[0]=g_pt[b3]; pN[1]=g_pt[b3+1]; pN[2]=g_pt[b3+2];
#pragma unroll
                for (int k = 0; k < 9; k++) RN[k] = g_Rt[b9+k];
                snN = s_snc[lane*SNC + (i-1)];
                csN = s_snc[lane*SNC + 6 + i];
            }
            float f0=Fb[i*6+0], f1=Fb[i*6+1], f2=Fb[i*6+2];
            s_misc[lane*MST + 14 + i] -= aC[0]*f0 + aC[1]*f1 + aC[2]*f2;
            if (i > 0){
                float E[9]; makeE_reg(aC, RC, snC, csC, E);
                float ftop[3] = {f0, f1, f2};
                float fbot[3] = {Fb[i*6+3], Fb[i*6+4], Fb[i*6+5]};
                float tm[3], tf[3], cp[3];
                mtv3(E, ftop, tm); mtv3(E, fbot, tf);
                cross3(pC, tf, cp);
                Fb[(i-1)*6+0] += tm[0]+cp[0];
                Fb[(i-1)*6+1] += tm[1]+cp[1];
                Fb[(i-1)*6+2] += tm[2]+cp[2];
                Fb[(i-1)*6+3] += tf[0];
                Fb[(i-1)*6+4] += tf[1];
                Fb[(i-1)*6+5] += tf[2];
#pragma unroll
                for (int k = 0; k < 3; k++){ aC[k]=aN[k]; pC[k]=pN[k]; }
#pragma unroll
                for (int k = 0; k < 9; k++) RC[k]=RN[k];
                snC=snN; csC=csN;
            }
        }
      }
    }

    __syncthreads();   // publish rhs

    if (act && role == 1){
        // ======== triangular solves + integrate + store (Mx in regs) ========
        float rhs[NJ], qv[NJ], qdv[NJ];
#pragma unroll
        for (int i = 0; i < NJ; i++){
            qv [i] = s_misc[lane*MST + i];
            qdv[i] = s_misc[lane*MST + 7 + i];
            rhs[i] = s_misc[lane*MST + 14 + i];
        }
        float y[NJ];
#pragma unroll
        for (int i = 0; i < NJ; i++){
            float s2 = rhs[i];
#pragma unroll
            for (int j = 0; j < NJ; j++) if (j < i) s2 -= Mx[MIX(i,j)]*y[j];
            y[i] = s2 * Mx[MIX(i,i)];
        }
        float z[NJ];
#pragma unroll
        for (int i = NJ-1; i >= 0; i--){
            float s2 = y[i];
#pragma unroll
            for (int j = NJ-1; j >= 0; j--) if (j > i) s2 -= Mx[MIX(j,i)]*z[j];
            z[i] = s2 * Mx[MIX(i,i)];
        }
        float o14[14];
#pragma unroll
        for (int i = 0; i < NJ; i++){
            float qdn = qdv[i] + DTF*z[i];
            o14[i]      = qv[i] + DTF*qdn;
            o14[NJ + i] = qdn;
        }
        float2* o2 = (float2*)(out + e*14);
#pragma unroll
        for (int i = 0; i < 7; i++){ float2 v; v.x = o14[2*i]; v.y = o14[2*i+1]; o2[i] = v; }
    }
}

extern "C" void kernel_launch(void* const* d_in, const int* in_sizes, int n_in,
                              void* d_out, int out_size, void* d_ws, size_t ws_size,
                              hipStream_t stream) {
    const float* x   = (const float*)d_in[0];
    const float* u   = (const float*)d_in[1];
    const float* ax  = (const float*)d_in[2];
    const float* Rt  = (const float*)d_in[3];
    const float* pt  = (const float*)d_in[4];
    const float* Isp = (const float*)d_in[5];
    float* out = (float*)d_out;
    int B = in_sizes[0] / 14;
    int grid = (B + 63) / 64;
    hipLaunchKernelGGL(panda_step, dim3(grid), dim3(128), 0, stream,
                       x, u, ax, Rt, pt, Isp, out, B);
}